// Round 1
// 157.027 us; speedup vs baseline: 1.2062x; 1.2062x over previous
//
#include <hip/hip_runtime.h>
#include <math.h>

#define B_  4
#define L_  2048
#define H_  8
#define D_  64
#define U_  40
#define HD  (H_*D_)   // 512

// ---------------------------------------------------------------------------
// Workspace (ws_size confirmed 256 MiB in r12 — KC=8 layout always fits):
//   pacc[1280*8*64]@0, pl[1280*8]@2621440, vmean@2662400, M@2670592,
//   mtop@2932736 -> 2,937,856 B
// ---------------------------------------------------------------------------
#define WS_NEED_KC8 2937856

// ---------------------------------------------------------------------------
// threefry2x32 (jax partitionable stream) — verified bit-exact round 4.
// randint(key(42),(2048,40),0,2048) = tf(k2,(0,j)).b1 ^ .b2 & 2047,
// k2 = tf((0,42),(0,1)) constexpr.
// ---------------------------------------------------------------------------
struct U2 { unsigned a, b; };

__host__ __device__ constexpr unsigned rotl32c(unsigned x, int r){
  return (x<<r)|(x>>(32-r));
}

__host__ __device__ constexpr U2 tf2x32(unsigned k0, unsigned k1,
                                        unsigned x0, unsigned x1)
{
  const unsigned k2 = k0 ^ k1 ^ 0x1BD11BDAu;
  const int rA[4] = {13,15,26,6};
  const int rB[4] = {17,29,16,24};
  x0 += k0; x1 += k1;
  for (int i=0;i<4;i++){ x0+=x1; x1=rotl32c(x1,rA[i]); x1^=x0; }
  x0 += k1; x1 += k2 + 1u;
  for (int i=0;i<4;i++){ x0+=x1; x1=rotl32c(x1,rB[i]); x1^=x0; }
  x0 += k2; x1 += k0 + 2u;
  for (int i=0;i<4;i++){ x0+=x1; x1=rotl32c(x1,rA[i]); x1^=x0; }
  x0 += k0; x1 += k1 + 3u;
  for (int i=0;i<4;i++){ x0+=x1; x1=rotl32c(x1,rB[i]); x1^=x0; }
  x0 += k1; x1 += k2 + 4u;
  for (int i=0;i<4;i++){ x0+=x1; x1=rotl32c(x1,rA[i]); x1^=x0; }
  x0 += k2; x1 += k0 + 5u;
  return U2{x0, x1};
}

// ---------------------------------------------------------------------------
// Dispatch 2 kernel: vmean(512 blocks) || M-scores(2048 blocks), fused.
// Independent work co-scheduled: vmean's V streaming hides in m's L2-gather
// stalls; saves a serialized dispatch. vmean blocks first (finish early).
// m part: wave = one (b,l), all 8 h; lane = h*8+d8 reads full 2 KB K rows
// contiguously; dot reduced over d8 (xor 1,2,4); vmax/vsum in-register
// across 40 samples; b = g&3 -> each XCD pair owns one 4 MB K[b] slab
// (r12-verified: m_kernel dropped 54 -> <42 us with this shape).
// ---------------------------------------------------------------------------
__global__ __launch_bounds__(256) void mvm_kernel(const float* __restrict__ q,
                                                  const float* __restrict__ k,
                                                  const float* __restrict__ v,
                                                  float* __restrict__ M,
                                                  float* __restrict__ vmean)
{
  int tid = threadIdx.x;
  int w = tid >> 6, lane = tid & 63;

  if (blockIdx.x < 512){
    // ---- vmean part: V column sums, atomics into pre-zeroed vmean ----
    int g = blockIdx.x;
    int bh = g & 31, chunk = g >> 5;
    int b = bh >> 3, h = bh & 7;
    int l0 = chunk*128 + w*32;
    float s = 0.f;
    for (int i=0;i<32;i++)
      s += v[(size_t)(b*L_ + l0 + i)*HD + h*D_ + lane];
    atomicAdd(&vmean[bh*D_ + lane], s);
    return;
  }

  // ---- M part ----
  int g    = blockIdx.x - 512;    // 0..2047, g = lblk*4 + b
  int b    = g & 3;
  int lblk = g >> 2;
  int l    = lblk*4 + w;
  int h    = lane >> 3, d8 = lane & 7;

  const float* qrow = q + (size_t)(b*L_ + l)*HD;
  float4 q0 = *(const float4*)(qrow + lane*8);
  float4 q1 = *(const float4*)(qrow + lane*8 + 4);

  constexpr U2 K2 = tf2x32(0u, 42u, 0u, 1u);
  int myidx = 0;
  if (lane < U_){
    U2 r = tf2x32(K2.a, K2.b, 0u, (unsigned)(l*U_ + lane));
    myidx = (int)((r.a ^ r.b) & 2047u);
  }

  const float* kb = k + (size_t)b*L_*HD;
  float vmax = -INFINITY, vsum = 0.f;
  #pragma unroll 8
  for (int s=0;s<U_;s++){
    int kidx = __shfl(myidx, s, 64);
    const float* kr = kb + (size_t)kidx*HD;
    float4 k0 = *(const float4*)(kr + lane*8);
    float4 k1 = *(const float4*)(kr + lane*8 + 4);
    float p = q0.x*k0.x + q0.y*k0.y + q0.z*k0.z + q0.w*k0.w
            + q1.x*k1.x + q1.y*k1.y + q1.z*k1.z + q1.w*k1.w;
    p += __shfl_xor(p, 1, 64);
    p += __shfl_xor(p, 2, 64);
    p += __shfl_xor(p, 4, 64);    // all 8 lanes of h now hold dot(s)
    vmax = fmaxf(vmax, p);
    vsum += p;
  }
  if (d8 == 0)
    M[(b*8 + h)*L_ + l] = vmax - vsum * (1.0f/(float)L_);
}

// ---------------------------------------------------------------------------
// Dispatch 3 kernel: topk(32 blocks) || init(4096 blocks), fused.
// topk rewritten as RADIX SELECT (this round): the 40-iteration serial
// argmax chain (~39 us of pure latency, 5.7% occupancy) is replaced by a
// 4-pass MSB-first 8-bit radix select over monotone-mapped float keys in
// LDS + one atomic compaction pass. Valid because top_k ORDER is
// irrelevant: indices are distinct, the scatter writes distinct rows, so
// only the selected SET must match (ties at the exact 40th key are
// counted exactly; tie-index choice is measure-zero on random floats).
// init's 16 MB streaming write fills the other 224 CUs; topk blocks first.
// ---------------------------------------------------------------------------
__global__ __launch_bounds__(256) void topk_init_kernel(const float* __restrict__ M,
                                                        const float* __restrict__ vmean,
                                                        int*   __restrict__ mtop,
                                                        float* __restrict__ out)
{
  int tid = threadIdx.x;

  if (blockIdx.x >= 32){
    // ---- init part: out[b][l][h][:] = vmean_sum * 1/2048 ----
    int i = (blockIdx.x - 32)*256 + tid;    // float4 index, 0..1048575
    int d4 = i & 15;
    int h  = (i >> 4) & 7;
    int bl = i >> 7;
    int b  = bl >> 11;
    float4 vm = ((const float4*)(vmean + (b*H_ + h)*D_))[d4];
    const float sc = 1.0f/(float)L_;
    float4 o; o.x = vm.x*sc; o.y = vm.y*sc; o.z = vm.z*sc; o.w = vm.w*sc;
    ((float4*)out)[i] = o;
    return;
  }

  // ---- topk part: 4x8-bit MSB-first radix select, then compaction ----
  __shared__ unsigned keys[L_];        // 8 KB: monotone-mapped float keys
  __shared__ unsigned hist[256];
  __shared__ unsigned sh_prefix, sh_need, sh_cgt, sh_ceq;
  int bh = blockIdx.x;

  // load + monotone map (order-preserving float->uint)
  #pragma unroll
  for (int i=0;i<8;i++){
    unsigned bits = __float_as_uint(M[bh*L_ + tid + 256*i]);
    keys[tid + 256*i] = (bits & 0x80000000u) ? ~bits : (bits | 0x80000000u);
  }
  if (tid == 0){ sh_prefix = 0u; sh_need = U_; sh_cgt = 0u; sh_ceq = 0u; }

  unsigned pmask = 0u;                 // bytes already fixed (above pass p)
  for (int p = 3; p >= 0; --p){
    hist[tid] = 0u;
    __syncthreads();                   // hist zeroed; sh_prefix/sh_need valid
    unsigned pref = sh_prefix;
    #pragma unroll
    for (int i=0;i<8;i++){
      unsigned key = keys[tid + 256*i];
      if ((key & pmask) == pref)
        atomicAdd(&hist[(key >> (8*p)) & 255u], 1u);
    }
    __syncthreads();

    if (tid < 64){
      // wave 0: suffix-scan 256 bins (4/lane), pick threshold bucket
      unsigned h0 = hist[tid*4+0], h1 = hist[tid*4+1];
      unsigned h2 = hist[tid*4+2], h3 = hist[tid*4+3];
      unsigned loc = h0+h1+h2+h3;
      unsigned s = loc;
      #pragma unroll
      for (int off=1; off<64; off<<=1){
        unsigned o = __shfl_down(s, off, 64);
        if (tid + off < 64) s += o;
      }                                // s = sum of bins in lanes >= tid
      unsigned need = sh_need;
      unsigned cum = s - loc;          // strictly-higher-lane total
      unsigned bsel = 0xFFFFFFFFu, nn = 0u;
      if (cum < need && cum + h3 >= need){ bsel = tid*4+3; nn = need - cum; }
      cum += h3;
      if (bsel==0xFFFFFFFFu && cum < need && cum + h2 >= need){ bsel = tid*4+2; nn = need - cum; }
      cum += h2;
      if (bsel==0xFFFFFFFFu && cum < need && cum + h1 >= need){ bsel = tid*4+1; nn = need - cum; }
      cum += h1;
      if (bsel==0xFFFFFFFFu && cum < need && cum + h0 >= need){ bsel = tid*4+0; nn = need - cum; }
      if (bsel != 0xFFFFFFFFu){        // exactly one lane qualifies
        sh_prefix = sh_prefix | (bsel << (8*p));
        sh_need = nn;
      }
    }
    __syncthreads();
    pmask |= 0xFFu << (8*p);
  }

  // sh_prefix == exact key of 40th-largest; sh_need == #ties to include
  unsigned K40 = sh_prefix;
  unsigned need = sh_need;
  #pragma unroll
  for (int i=0;i<8;i++){
    int idx = tid + 256*i;
    unsigned key = keys[idx];
    if (key > K40){
      unsigned pos = atomicAdd(&sh_cgt, 1u);       // pos < U_-need
      mtop[bh*U_ + pos] = idx;
    } else if (key == K40){
      unsigned e = atomicAdd(&sh_ceq, 1u);
      if (e < need) mtop[bh*U_ + (U_ - need) + e] = idx;
    }
  }
}

// ---------------------------------------------------------------------------
// Kernel: attention partials, stored exclusive slices (no atomics — r9).
// Grid = 32 bh x KC kc x 2 qg; KC=8 (512 blocks = 2/CU, LDS-capped).
// Block: 4 waves; wave owns 5 queries; nt=16/KC runtime-trip 128-key tiles
// (runtime loop + __launch_bounds__(256,3) = proven anti-spill, VGPR 84).
// Kt pad-68 (0 conflicts), Vt in LDS, psQ overlays Kt after scores.
// p = exp(s/8), no max-shift (validated r7-r12). bh = g&31 -> all 16
// blocks of a bh on XCD bh%8: per-XCD K+V working set = 4 MB = L2.
// ---------------------------------------------------------------------------
__global__ __launch_bounds__(256, 3) void attn_kernel(const float* __restrict__ q,
                                                      const float* __restrict__ k,
                                                      const float* __restrict__ v,
                                                      const int*   __restrict__ mtop,
                                                      float* __restrict__ pacc,
                                                      float* __restrict__ pl,
                                                      int nt, int KC)
{
  __shared__ float sh[128*68 + 128*64 + 20*64];  // Kt + Vt + Qs = 72,704 B
  float* Kt  = sh;                 // psQ[20][128] overlays after scores
  float* Vt  = sh + 128*68;
  float* Qs  = sh + 128*68 + 128*64;
  float* psQ = sh;

  int g  = blockIdx.x;             // 64*KC
  int bh = g & 31, j = g >> 5;
  int kc = j >> 1, qg = j & 1;
  int b = bh >> 3, h = bh & 7;
  int tid = threadIdx.x, w = tid >> 6, lane = tid & 63;

  // stage Qs: 20 rows x 16 float4 = 320 float4
  #pragma unroll
  for (int c=0;c<2;c++){
    int flat = c*256 + tid;
    if (flat < 320){
      int row = flat >> 4, col = flat & 15;
      int lstar = mtop[bh*U_ + qg*20 + row];
      ((float4*)(Qs + row*64))[col] =
        ((const float4*)(q + (size_t)(b*L_ + lstar)*HD + h*D_))[col];
    }
  }

  float acc[5], lsum[5];
  #pragma unroll
  for (int qq=0;qq<5;qq++){ acc[qq] = 0.f; lsum[qq] = 0.f; }

  for (int tt=0; tt<nt; ++tt){     // runtime trip count pins code shape
    int kt = (kc*nt + tt)*128;
    __syncthreads();               // Qs ready / prior tile's psQ+Vt reads done
    #pragma unroll
    for (int c=0;c<8;c++){
      int flat = c*256 + tid;
      int row = flat >> 4, col = flat & 15;
      ((float4*)(Kt + row*68))[col] =
        ((const float4*)(k + (size_t)(b*L_ + kt + row)*HD + h*D_))[col];
      ((float4*)(Vt + row*64))[col] =
        ((const float4*)(v + (size_t)(b*L_ + kt + row)*HD + h*D_))[col];
    }
    __syncthreads();

    // scores: 5 queries x 2 keys per lane
    float s0[5], s1[5];
    #pragma unroll
    for (int qq=0;qq<5;qq++){ s0[qq] = 0.f; s1[qq] = 0.f; }
    const float* kr0 = Kt + lane*68;
    const float* kr1 = Kt + (lane+64)*68;
    #pragma unroll
    for (int t=0;t<16;t++){
      float4 k0 = ((const float4*)kr0)[t];
      float4 k1 = ((const float4*)kr1)[t];
      #pragma unroll
      for (int qq=0;qq<5;qq++){
        float4 qf = ((const float4*)(Qs + (w*5+qq)*64))[t];
        s0[qq] += k0.x*qf.x + k0.y*qf.y + k0.z*qf.z + k0.w*qf.w;
        s1[qq] += k1.x*qf.x + k1.y*qf.y + k1.z*qf.z + k1.w*qf.w;
      }
    }
    __syncthreads();   // Kt reads done before psQ overlay

    #pragma unroll
    for (int qq=0;qq<5;qq++){
      float p0 = __expf(s0[qq]*0.125f);
      float p1 = __expf(s1[qq]*0.125f);
      psQ[(w*5+qq)*128 + lane]      = p0;
      psQ[(w*5+qq)*128 + lane + 64] = p1;
      lsum[qq] += p0 + p1;         // per-lane; reduced once in epilogue
    }
    __syncthreads();   // psQ visible before PV / next restage

    // PV: lane = output dim; wave's 5 queries, all 128 keys from Vt
    for (int k4=0;k4<32;k4++){
      float v0 = Vt[(4*k4+0)*64 + lane];
      float v1 = Vt[(4*k4+1)*64 + lane];
      float v2 = Vt[(4*k4+2)*64 + lane];
      float v3 = Vt[(4*k4+3)*64 + lane];
      #pragma unroll
      for (int qq=0;qq<5;qq++){
        float4 pp = ((const float4*)(psQ + (w*5+qq)*128))[k4];
        acc[qq] += pp.x*v0 + pp.y*v1 + pp.z*v2 + pp.w*v3;
      }
    }
  }

  // epilogue: exclusive (gu,kc) partial slice — no atomics
  #pragma unroll
  for (int qq=0;qq<5;qq++){
    float ls = lsum[qq];
    #pragma unroll
    for (int off=32; off; off>>=1) ls += __shfl_xor(ls, off, 64);
    int gu = bh*U_ + qg*20 + w*5 + qq;
    pacc[(size_t)(gu*KC + kc)*64 + lane] = acc[qq];
    if (lane == 0) pl[gu*KC + kc] = ls;
  }
}

// ---------------------------------------------------------------------------
// Kernel: sum KC partials per (bh,u), normalize, scatter selected rows.
// ---------------------------------------------------------------------------
__global__ __launch_bounds__(256) void combine_kernel(const int* __restrict__ mtop,
                                                      const float* __restrict__ pacc,
                                                      const float* __restrict__ pl,
                                                      float* __restrict__ out,
                                                      int KC)
{
  int gu = blockIdx.x*4 + (threadIdx.x >> 6);  // 0..1279
  int lane = threadIdx.x & 63;
  int bh = gu / U_, u = gu - bh*U_;
  float a = 0.f, L = 0.f;
  for (int c=0;c<KC;c++){
    a += pacc[(size_t)(gu*KC + c)*64 + lane];
    L += pl[gu*KC + c];
  }
  int b = bh >> 3, h = bh & 7;
  int lstar = mtop[bh*U_ + u];
  out[(size_t)(b*L_ + lstar)*HD + h*D_ + lane] = a / L;
}

// ---------------------------------------------------------------------------
extern "C" void kernel_launch(void* const* d_in, const int* in_sizes, int n_in,
                              void* d_out, int out_size, void* d_ws, size_t ws_size,
                              hipStream_t stream)
{
  const float* q = (const float*)d_in[0];
  const float* k = (const float*)d_in[1];
  const float* v = (const float*)d_in[2];
  float* out = (float*)d_out;

  int KC = (ws_size >= (size_t)WS_NEED_KC8) ? 8 : 4;
  int nt = 16 / KC;

  size_t o_pl    = (size_t)1280*KC*64*4;
  size_t o_vmean = o_pl + (size_t)1280*KC*4;
  size_t o_M     = o_vmean + 2048*4;
  size_t o_mtop  = o_M + 65536*4;

  float* pacc  = (float*)d_ws;
  float* pl    = (float*)((char*)d_ws + o_pl);
  float* vmean = (float*)((char*)d_ws + o_vmean);
  float* M     = (float*)((char*)d_ws + o_M);
  int*   mtop  = (int*)  ((char*)d_ws + o_mtop);

  hipMemsetAsync(vmean, 0, 2048*sizeof(float), stream);
  mvm_kernel      <<<2560,  256, 0, stream>>>(q, k, v, M, vmean);
  topk_init_kernel<<<4128,  256, 0, stream>>>(M, vmean, mtop, out);
  attn_kernel     <<<64*KC, 256, 0, stream>>>(q, k, v, mtop, pacc, pl, nt, KC);
  combine_kernel  <<<320,   256, 0, stream>>>(mtop, pacc, pl, out, KC);
}